// Round 1
// baseline (7216.422 us; speedup 1.0000x reference)
//
#include <hip/hip_runtime.h>
#include <stdint.h>

#define DIN 512
#define DOUT 512

typedef short bf16x8 __attribute__((ext_vector_type(8)));
typedef float floatx4 __attribute__((ext_vector_type(4)));

static __device__ __forceinline__ ushort f2bf(float f) {
  uint32_t u = __float_as_uint(f);
  u += 0x7FFFu + ((u >> 16) & 1u);   // RTNE; inputs are finite/normal here
  return (ushort)(u >> 16);
}

// ---------------- W fp32 -> bf16 ----------------
__global__ __launch_bounds__(256) void wconv_kernel(const float* __restrict__ W,
                                                    ushort* __restrict__ Wbf) {
  int i = blockIdx.x * 256 + threadIdx.x;  // grid sized exactly to DOUT*DIN
  Wbf[i] = f2bf(W[i]);
}

// ---------------- logmap0 + cast to bf16 ----------------
// One wave per row. tangent = atanh(clip(||x||)) * x / clip(||x||)
__global__ __launch_bounds__(256) void logmap_kernel(const float* __restrict__ x,
                                                     ushort* __restrict__ tanb,
                                                     int N) {
  int row = blockIdx.x * 4 + (threadIdx.x >> 6);
  if (row >= N) return;
  int lane = threadIdx.x & 63;
  const float4* xr = (const float4*)(x + (size_t)row * DIN);
  float4 v0 = xr[lane * 2 + 0];
  float4 v1 = xr[lane * 2 + 1];
  float ss = v0.x * v0.x + v0.y * v0.y + v0.z * v0.z + v0.w * v0.w +
             v1.x * v1.x + v1.y * v1.y + v1.z * v1.z + v1.w * v1.w;
#pragma unroll
  for (int m = 32; m >= 1; m >>= 1) ss += __shfl_xor(ss, m, 64);
  float n = sqrtf(ss);
  float nc = fminf(fmaxf(n, 1e-7f), 1.0f - 1e-7f);
  float scale = atanhf(nc) / nc;
  union { ushort s[8]; uint4 v; } o;
  o.s[0] = f2bf(v0.x * scale); o.s[1] = f2bf(v0.y * scale);
  o.s[2] = f2bf(v0.z * scale); o.s[3] = f2bf(v0.w * scale);
  o.s[4] = f2bf(v1.x * scale); o.s[5] = f2bf(v1.y * scale);
  o.s[6] = f2bf(v1.z * scale); o.s[7] = f2bf(v1.w * scale);
  *(uint4*)(tanb + (size_t)row * DIN + lane * 8) = o.v;
}

// ---------------- GEMM: H[m][n] = sum_k tan[m][k]*W[n][k] + b[n] ----------------
// 128x128 tile per block, 256 threads = 4 waves, each wave 64x64 (4x4 MFMA tiles).
// mfma_f32_16x16x32_bf16: A-op A[m=lane&15][k=(lane>>4)*8+j]; B-op B[k][n=lane&15]
// with same k indexing; D: col=lane&15, row=(lane>>4)*4+reg (verified m89/m91).
#define BM 128
#define BN 128
#define BK 32
__global__ __launch_bounds__(256) void gemm_kernel(const ushort* __restrict__ A,
                                                   const ushort* __restrict__ Bw,
                                                   const float* __restrict__ bias,
                                                   float* __restrict__ H, int M) {
  __shared__ __align__(16) ushort As[BM * BK];
  __shared__ __align__(16) ushort Bs[BN * BK];
  int tid = threadIdx.x;
  int wave = tid >> 6, lane = tid & 63;
  int wm = (wave >> 1) * 64, wn = (wave & 1) * 64;
  int m0 = blockIdx.x * BM, n0 = blockIdx.y * BN;

  floatx4 acc[4][4] = {};
  int fr = lane & 15, fk = (lane >> 4) * 8;

  for (int k0 = 0; k0 < DIN; k0 += BK) {
#pragma unroll
    for (int r = 0; r < 2; r++) {
      int slot = r * 256 + tid;       // 512 slots x 16B = both halves of a tile
      int row = slot >> 2;            // 64B (=32 bf16) per row, 4 slots/row
      int kc = (slot & 3) * 8;
      int gm = m0 + row; if (gm > M - 1) gm = M - 1;   // clamp tail rows
      uint4 av = *(const uint4*)(A + (size_t)gm * DIN + k0 + kc);
      uint4 bv = *(const uint4*)(Bw + (size_t)(n0 + row) * DIN + k0 + kc);
      *(uint4*)(As + slot * 8) = av;
      *(uint4*)(Bs + slot * 8) = bv;
    }
    __syncthreads();
    bf16x8 afrag[4], bfrag[4];
#pragma unroll
    for (int t = 0; t < 4; t++) {
      afrag[t] = *(const bf16x8*)(As + (wm + t * 16 + fr) * BK + fk);
      bfrag[t] = *(const bf16x8*)(Bs + (wn + t * 16 + fr) * BK + fk);
    }
#pragma unroll
    for (int mt = 0; mt < 4; mt++)
#pragma unroll
      for (int nt = 0; nt < 4; nt++)
        acc[mt][nt] = __builtin_amdgcn_mfma_f32_16x16x32_bf16(
            afrag[mt], bfrag[nt], acc[mt][nt], 0, 0, 0);
    __syncthreads();
  }

  int col = lane & 15, rq = (lane >> 4) * 4;
#pragma unroll
  for (int nt = 0; nt < 4; nt++) {
    int n = n0 + wn + nt * 16 + col;
    float bb = bias[n];
#pragma unroll
    for (int mt = 0; mt < 4; mt++) {
#pragma unroll
      for (int r = 0; r < 4; r++) {
        int m = m0 + wm + mt * 16 + rq + r;
        if (m < M) H[(size_t)m * DOUT + n] = acc[mt][nt][r] + bb;
      }
    }
  }
}

// ---------------- scatter-add: sums[dst] += h[src], deg[dst] += 1 ----------------
__global__ __launch_bounds__(256) void scatter_kernel(const float* __restrict__ h,
                                                      const int* __restrict__ src,
                                                      const int* __restrict__ dst,
                                                      float* __restrict__ sums,
                                                      float* __restrict__ deg, int E) {
  int e = blockIdx.x * 4 + (threadIdx.x >> 6);
  if (e >= E) return;
  int lane = threadIdx.x & 63;
  int s = src[e];
  int d = dst[e];
  const float4* hr = (const float4*)(h + (size_t)s * DOUT);
  float* dr = sums + (size_t)d * DOUT;
  float4 a = hr[lane];
  float4 c = hr[lane + 64];
  unsafeAtomicAdd(dr + lane * 4 + 0, a.x);
  unsafeAtomicAdd(dr + lane * 4 + 1, a.y);
  unsafeAtomicAdd(dr + lane * 4 + 2, a.z);
  unsafeAtomicAdd(dr + lane * 4 + 3, a.w);
  unsafeAtomicAdd(dr + 256 + lane * 4 + 0, c.x);
  unsafeAtomicAdd(dr + 256 + lane * 4 + 1, c.y);
  unsafeAtomicAdd(dr + 256 + lane * 4 + 2, c.z);
  unsafeAtomicAdd(dr + 256 + lane * 4 + 3, c.w);
  if (lane == 0) unsafeAtomicAdd(deg + d, 1.0f);
}

// ---------------- finalize: neigh = sums/max(deg,1); out = expmap0(neigh) ----------------
__global__ __launch_bounds__(256) void finalize_kernel(float* __restrict__ io,
                                                       const float* __restrict__ deg,
                                                       int N) {
  int row = blockIdx.x * 4 + (threadIdx.x >> 6);
  if (row >= N) return;
  int lane = threadIdx.x & 63;
  float inv = 1.0f / fmaxf(deg[row], 1.0f);
  float4* r = (float4*)(io + (size_t)row * DOUT);
  float4 v0 = r[lane * 2 + 0];
  float4 v1 = r[lane * 2 + 1];
  v0.x *= inv; v0.y *= inv; v0.z *= inv; v0.w *= inv;
  v1.x *= inv; v1.y *= inv; v1.z *= inv; v1.w *= inv;
  float ss = v0.x * v0.x + v0.y * v0.y + v0.z * v0.z + v0.w * v0.w +
             v1.x * v1.x + v1.y * v1.y + v1.z * v1.z + v1.w * v1.w;
#pragma unroll
  for (int m = 32; m >= 1; m >>= 1) ss += __shfl_xor(ss, m, 64);
  float n = fmaxf(sqrtf(ss), 1e-7f);
  float sc = tanhf(n) / n;
  v0.x *= sc; v0.y *= sc; v0.z *= sc; v0.w *= sc;
  v1.x *= sc; v1.y *= sc; v1.z *= sc; v1.w *= sc;
  r[lane * 2 + 0] = v0;
  r[lane * 2 + 1] = v1;
}

extern "C" void kernel_launch(void* const* d_in, const int* in_sizes, int n_in,
                              void* d_out, int out_size, void* d_ws, size_t ws_size,
                              hipStream_t stream) {
  const float* x = (const float*)d_in[0];
  const int* src = (const int*)d_in[1];
  const int* dst = (const int*)d_in[2];
  const float* W = (const float*)d_in[3];
  const float* b = (const float*)d_in[4];
  int N = in_sizes[0] / DIN;
  int E = in_sizes[1];
  float* out = (float*)d_out;

  // workspace layout
  char* ws = (char*)d_ws;
  ushort* Wbf = (ushort*)ws;                               // 512*512*2 = 512 KiB
  size_t off = (size_t)DOUT * DIN * 2;
  ushort* tanb = (ushort*)(ws + off);                      // N*512*2
  off += (size_t)N * DIN * 2; off = (off + 255) & ~(size_t)255;
  float* deg = (float*)(ws + off);                         // N*4
  off += (size_t)N * 4; off = (off + 255) & ~(size_t)255;
  float* h = (float*)(ws + off);                           // N*512*4

  hipMemsetAsync(out, 0, (size_t)out_size * 4, stream);    // sums accumulate in d_out
  hipMemsetAsync(deg, 0, (size_t)N * 4, stream);

  wconv_kernel<<<(DOUT * DIN) / 256, 256, 0, stream>>>(W, Wbf);
  logmap_kernel<<<(N + 3) / 4, 256, 0, stream>>>(x, tanb, N);
  dim3 g((N + BM - 1) / BM, DOUT / BN);
  gemm_kernel<<<g, 256, 0, stream>>>(tanb, Wbf, b, h, N);
  scatter_kernel<<<(E + 3) / 4, 256, 0, stream>>>(h, src, dst, out, deg, E);
  finalize_kernel<<<(N + 3) / 4, 256, 0, stream>>>(out, deg, N);
}

// Round 2
// 762.116 us; speedup vs baseline: 9.4689x; 9.4689x over previous
//
#include <hip/hip_runtime.h>
#include <stdint.h>

#define DIN 512
#define DOUT 512

typedef short bf16x8 __attribute__((ext_vector_type(8)));
typedef float floatx4 __attribute__((ext_vector_type(4)));

static __device__ __forceinline__ ushort f2bf(float f) {
  uint32_t u = __float_as_uint(f);
  u += 0x7FFFu + ((u >> 16) & 1u);   // RTNE; values are finite/normal here
  return (ushort)(u >> 16);
}

// ---------------- W fp32 -> bf16 ----------------
__global__ __launch_bounds__(256) void wconv_kernel(const float* __restrict__ W,
                                                    ushort* __restrict__ Wbf) {
  int i = blockIdx.x * 256 + threadIdx.x;  // grid sized exactly to DOUT*DIN
  Wbf[i] = f2bf(W[i]);
}

// ---------------- logmap0 + cast to bf16 ----------------
__global__ __launch_bounds__(256) void logmap_kernel(const float* __restrict__ x,
                                                     ushort* __restrict__ tanb,
                                                     int N) {
  int row = blockIdx.x * 4 + (threadIdx.x >> 6);
  if (row >= N) return;
  int lane = threadIdx.x & 63;
  const float4* xr = (const float4*)(x + (size_t)row * DIN);
  float4 v0 = xr[lane * 2 + 0];
  float4 v1 = xr[lane * 2 + 1];
  float ss = v0.x * v0.x + v0.y * v0.y + v0.z * v0.z + v0.w * v0.w +
             v1.x * v1.x + v1.y * v1.y + v1.z * v1.z + v1.w * v1.w;
#pragma unroll
  for (int m = 32; m >= 1; m >>= 1) ss += __shfl_xor(ss, m, 64);
  float n = sqrtf(ss);
  float nc = fminf(fmaxf(n, 1e-7f), 1.0f - 1e-7f);
  float scale = atanhf(nc) / nc;
  union { ushort s[8]; uint4 v; } o;
  o.s[0] = f2bf(v0.x * scale); o.s[1] = f2bf(v0.y * scale);
  o.s[2] = f2bf(v0.z * scale); o.s[3] = f2bf(v0.w * scale);
  o.s[4] = f2bf(v1.x * scale); o.s[5] = f2bf(v1.y * scale);
  o.s[6] = f2bf(v1.z * scale); o.s[7] = f2bf(v1.w * scale);
  *(uint4*)(tanb + (size_t)row * DIN + lane * 8) = o.v;
}

// ---------------- GEMM: Hb[m][n] = bf16( sum_k tan[m][k]*W[n][k] + b[n] ) ----------------
#define BM 128
#define BN 128
#define BK 32
__global__ __launch_bounds__(256) void gemm_kernel(const ushort* __restrict__ A,
                                                   const ushort* __restrict__ Bw,
                                                   const float* __restrict__ bias,
                                                   ushort* __restrict__ Hb, int M) {
  __shared__ __align__(16) ushort As[BM * BK];
  __shared__ __align__(16) ushort Bs[BN * BK];
  int tid = threadIdx.x;
  int wave = tid >> 6, lane = tid & 63;
  int wm = (wave >> 1) * 64, wn = (wave & 1) * 64;
  int m0 = blockIdx.x * BM, n0 = blockIdx.y * BN;

  floatx4 acc[4][4] = {};
  int fr = lane & 15, fk = (lane >> 4) * 8;

  for (int k0 = 0; k0 < DIN; k0 += BK) {
#pragma unroll
    for (int r = 0; r < 2; r++) {
      int slot = r * 256 + tid;
      int row = slot >> 2;
      int kc = (slot & 3) * 8;
      int gm = m0 + row; if (gm > M - 1) gm = M - 1;   // clamp tail rows
      uint4 av = *(const uint4*)(A + (size_t)gm * DIN + k0 + kc);
      uint4 bv = *(const uint4*)(Bw + (size_t)(n0 + row) * DIN + k0 + kc);
      *(uint4*)(As + slot * 8) = av;
      *(uint4*)(Bs + slot * 8) = bv;
    }
    __syncthreads();
    bf16x8 afrag[4], bfrag[4];
#pragma unroll
    for (int t = 0; t < 4; t++) {
      afrag[t] = *(const bf16x8*)(As + (wm + t * 16 + fr) * BK + fk);
      bfrag[t] = *(const bf16x8*)(Bs + (wn + t * 16 + fr) * BK + fk);
    }
#pragma unroll
    for (int mt = 0; mt < 4; mt++)
#pragma unroll
      for (int nt = 0; nt < 4; nt++)
        acc[mt][nt] = __builtin_amdgcn_mfma_f32_16x16x32_bf16(
            afrag[mt], bfrag[nt], acc[mt][nt], 0, 0, 0);
    __syncthreads();
  }

  int col = lane & 15, rq = (lane >> 4) * 4;
#pragma unroll
  for (int nt = 0; nt < 4; nt++) {
    int n = n0 + wn + nt * 16 + col;
    float bb = bias[n];
#pragma unroll
    for (int mt = 0; mt < 4; mt++) {
#pragma unroll
      for (int r = 0; r < 4; r++) {
        int m = m0 + wm + mt * 16 + rq + r;
        if (m < M) Hb[(size_t)m * DOUT + n] = f2bf(acc[mt][nt][r] + bb);
      }
    }
  }
}

// ---------------- CSR build ----------------
__global__ __launch_bounds__(256) void degcount_kernel(const int* __restrict__ dst,
                                                       int* __restrict__ degi, int E) {
  int e = blockIdx.x * 256 + threadIdx.x;
  if (e < E) atomicAdd(&degi[dst[e]], 1);
}

__global__ __launch_bounds__(256) void scan1_kernel(const int* __restrict__ degi,
                                                    int* __restrict__ offs,
                                                    int* __restrict__ bsum, int N) {
  __shared__ int s[256];
  int tx = threadIdx.x;
  int i = blockIdx.x * 256 + tx;
  int v = (i < N) ? degi[i] : 0;
  s[tx] = v;
  __syncthreads();
#pragma unroll
  for (int d = 1; d < 256; d <<= 1) {
    int t = (tx >= d) ? s[tx - d] : 0;
    __syncthreads();
    s[tx] += t;
    __syncthreads();
  }
  if (i < N) offs[i] = s[tx] - v;            // exclusive within block
  if (tx == 255) bsum[blockIdx.x] = s[255];  // block total
}

__global__ __launch_bounds__(1024) void scan2_kernel(int* __restrict__ bsum, int B) {
  __shared__ int s[1024];
  int tx = threadIdx.x;
  int v = (tx < B) ? bsum[tx] : 0;
  s[tx] = v;
  __syncthreads();
#pragma unroll
  for (int d = 1; d < 1024; d <<= 1) {
    int t = (tx >= d) ? s[tx - d] : 0;
    __syncthreads();
    s[tx] += t;
    __syncthreads();
  }
  if (tx < B) bsum[tx] = s[tx] - v;          // exclusive block offsets
}

__global__ __launch_bounds__(256) void scan3_kernel(int* __restrict__ offs,
                                                    const int* __restrict__ bsum,
                                                    int* __restrict__ cursor, int N) {
  int i = blockIdx.x * 256 + threadIdx.x;
  if (i < N) {
    int o = offs[i] + bsum[blockIdx.x];
    offs[i] = o;
    cursor[i] = o;
  }
}

__global__ __launch_bounds__(256) void filladj_kernel(const int* __restrict__ src,
                                                      const int* __restrict__ dst,
                                                      int* __restrict__ cursor,
                                                      int* __restrict__ adj, int E) {
  int e = blockIdx.x * 256 + threadIdx.x;
  if (e < E) {
    int pos = atomicAdd(&cursor[dst[e]], 1);
    adj[pos] = src[e];
  }
}

// ---------------- aggregate + mean + expmap0 (one wave per node) ----------------
static __device__ __forceinline__ void accum8(float* acc, uint4 v) {
  acc[0] += __uint_as_float(v.x << 16); acc[1] += __uint_as_float(v.x & 0xFFFF0000u);
  acc[2] += __uint_as_float(v.y << 16); acc[3] += __uint_as_float(v.y & 0xFFFF0000u);
  acc[4] += __uint_as_float(v.z << 16); acc[5] += __uint_as_float(v.z & 0xFFFF0000u);
  acc[6] += __uint_as_float(v.w << 16); acc[7] += __uint_as_float(v.w & 0xFFFF0000u);
}

__global__ __launch_bounds__(256) void aggregate_kernel(const ushort* __restrict__ hb,
                                                        const int* __restrict__ adj,
                                                        const int* __restrict__ offs,
                                                        const int* __restrict__ degi,
                                                        float* __restrict__ out, int N) {
  int row = blockIdx.x * 4 + (threadIdx.x >> 6);
  if (row >= N) return;
  int lane = threadIdx.x & 63;
  int dg = degi[row];
  int base = offs[row];
  float acc[8] = {0.f, 0.f, 0.f, 0.f, 0.f, 0.f, 0.f, 0.f};
  int j = 0;
  for (; j + 4 <= dg; j += 4) {
    int s0 = __builtin_amdgcn_readfirstlane(adj[base + j + 0]);
    int s1 = __builtin_amdgcn_readfirstlane(adj[base + j + 1]);
    int s2 = __builtin_amdgcn_readfirstlane(adj[base + j + 2]);
    int s3 = __builtin_amdgcn_readfirstlane(adj[base + j + 3]);
    uint4 a = *(const uint4*)(hb + (size_t)s0 * DOUT + lane * 8);
    uint4 b = *(const uint4*)(hb + (size_t)s1 * DOUT + lane * 8);
    uint4 c = *(const uint4*)(hb + (size_t)s2 * DOUT + lane * 8);
    uint4 d = *(const uint4*)(hb + (size_t)s3 * DOUT + lane * 8);
    accum8(acc, a); accum8(acc, b); accum8(acc, c); accum8(acc, d);
  }
  for (; j < dg; j++) {
    int s = __builtin_amdgcn_readfirstlane(adj[base + j]);
    uint4 a = *(const uint4*)(hb + (size_t)s * DOUT + lane * 8);
    accum8(acc, a);
  }
  float inv = 1.0f / fmaxf((float)dg, 1.0f);
  float ss = 0.f;
#pragma unroll
  for (int k = 0; k < 8; k++) ss += acc[k] * acc[k];
#pragma unroll
  for (int m = 32; m >= 1; m >>= 1) ss += __shfl_xor(ss, m, 64);
  float n = fmaxf(inv * sqrtf(ss), 1e-7f);   // ||mean||, clamped like reference
  float sc = tanhf(n) / n * inv;
  float4 o0, o1;
  o0.x = acc[0] * sc; o0.y = acc[1] * sc; o0.z = acc[2] * sc; o0.w = acc[3] * sc;
  o1.x = acc[4] * sc; o1.y = acc[5] * sc; o1.z = acc[6] * sc; o1.w = acc[7] * sc;
  float* orow = out + (size_t)row * DOUT + lane * 8;
  *(float4*)(orow + 0) = o0;
  *(float4*)(orow + 4) = o1;
}

extern "C" void kernel_launch(void* const* d_in, const int* in_sizes, int n_in,
                              void* d_out, int out_size, void* d_ws, size_t ws_size,
                              hipStream_t stream) {
  const float* x = (const float*)d_in[0];
  const int* src = (const int*)d_in[1];
  const int* dst = (const int*)d_in[2];
  const float* W = (const float*)d_in[3];
  const float* b = (const float*)d_in[4];
  int N = in_sizes[0] / DIN;
  int E = in_sizes[1];
  float* out = (float*)d_out;

  // workspace layout
  char* ws = (char*)d_ws;
  size_t off = 0;
  ushort* Wbf = (ushort*)(ws + off); off += (size_t)DOUT * DIN * 2;
  ushort* tanb = (ushort*)(ws + off); off += (size_t)N * DIN * 2;
  ushort* hb = (ushort*)(ws + off); off += (size_t)N * DIN * 2;
  off = (off + 255) & ~(size_t)255;
  int* degi = (int*)(ws + off); off += (size_t)N * 4;
  off = (off + 255) & ~(size_t)255;
  int* offs = (int*)(ws + off); off += (size_t)N * 4;
  off = (off + 255) & ~(size_t)255;
  int* cursor = (int*)(ws + off); off += (size_t)N * 4;
  off = (off + 255) & ~(size_t)255;
  int* bsum = (int*)(ws + off); off += 1024 * 4;
  int* adj = (int*)(ws + off); off += (size_t)E * 4;

  hipMemsetAsync(degi, 0, (size_t)N * 4, stream);

  wconv_kernel<<<(DOUT * DIN) / 256, 256, 0, stream>>>(W, Wbf);
  logmap_kernel<<<(N + 3) / 4, 256, 0, stream>>>(x, tanb, N);
  dim3 g((N + BM - 1) / BM, DOUT / BN);
  gemm_kernel<<<g, 256, 0, stream>>>(tanb, Wbf, b, hb, N);

  int B1 = (N + 255) / 256;  // <= 1024 blocks for N <= 262144
  degcount_kernel<<<(E + 255) / 256, 256, 0, stream>>>(dst, degi, E);
  scan1_kernel<<<B1, 256, 0, stream>>>(degi, offs, bsum, N);
  scan2_kernel<<<1, 1024, 0, stream>>>(bsum, B1);
  scan3_kernel<<<B1, 256, 0, stream>>>(offs, bsum, cursor, N);
  filladj_kernel<<<(E + 255) / 256, 256, 0, stream>>>(src, dst, cursor, adj, E);

  aggregate_kernel<<<(N + 3) / 4, 256, 0, stream>>>(hb, adj, offs, degi, out, N);
}